// Round 2
// baseline (155.491 us; speedup 1.0000x reference)
//
#include <hip/hip_runtime.h>
#include <hip/hip_bf16.h>
#include <math.h>
#include <stdint.h>

// Problem: B=64, SQ=64, SD=512, H=128
#define BB 64
#define SQN 64
#define SDN 512
#define HH 128

typedef __attribute__((ext_vector_type(8))) short bf16x8;     // 8 bf16 = 4 VGPRs
typedef __attribute__((ext_vector_type(16))) float f32x16;    // 16 acc regs

__device__ __forceinline__ short f2bf(float f) {
  union { float f; unsigned u; } x; x.f = f;
  unsigned r = x.u + 0x7fffu + ((x.u >> 16) & 1u);   // RNE
  return (short)(r >> 16);
}

__device__ __forceinline__ void gl_lds16(const short* g, short* l) {
  __builtin_amdgcn_global_load_lds(
      (const __attribute__((address_space(1))) unsigned int*)g,
      (__attribute__((address_space(3))) unsigned int*)l, 16, 0, 0);
}

// ---- fused compact + fp32->bf16 convert ------------------------------------
// d-blocks (8 rows each) recompute their own perm slice with an in-wave
// ballot/popcount scan of the 512-entry mask row (L2-hot, ~300cyc, hidden
// under the block's gather latency). Removes the separate compact_meta
// dispatch. One block per bs (j0==0) publishes nchunks/nvalid for maxsim.
// Rows are written only up to pad32 = (valid+31)&~31: maxsim's trimmed
// staging never touches [pad32, pad128).
__global__ __launch_bounds__(256)
void convert_all(const float* __restrict__ q, const float* __restrict__ dp,
                 const float* __restrict__ dn,
                 const int* __restrict__ mp, const int* __restrict__ mn,
                 short* __restrict__ oq, short* __restrict__ od,
                 int* __restrict__ nchunks, int* __restrict__ nvalid,
                 int* __restrict__ counter) {
  const int D_BLOCKS = (2 * BB * SDN) / 8;   // 8192 (8 rows/block, 32 thr/row)
  if (blockIdx.x < D_BLOCKS) {
    const int bs = blockIdx.x >> 6;          // 64 blocks per (side*64+b)
    const int j0 = (blockIdx.x & 63) * 8;    // first compacted row of block
    const int side = bs >> 6, b = bs & 63;
    const int* mask = (side ? mn : mp) + b * SDN;

    __shared__ int s_perm[8];
    __shared__ int s_pad32;

    if (threadIdx.x < 64) {                  // wave 0: exclusive scan of mask
      const int ln = threadIdx.x;
      int mreg[8];
      #pragma unroll
      for (int it = 0; it < 8; ++it) mreg[it] = mask[it * 64 + ln];
      int run = 0;
      #pragma unroll
      for (int it = 0; it < 8; ++it) {
        unsigned long long bal = __ballot(mreg[it] != 0);
        int pos = run + __popcll(bal & ((1ull << ln) - 1ull));
        if (mreg[it]) {
          unsigned rel = (unsigned)(pos - j0);
          if (rel < 8u) s_perm[rel] = it * 64 + ln;
        }
        run += (int)__popcll(bal);
      }
      if (ln < 8 && j0 + ln >= run) s_perm[ln] = -1;   // zero-fill slots
      if (ln == 0) {
        s_pad32 = (run + 31) & ~31;
        if (j0 == 0) {                       // one writer per bs
          nchunks[bs] = ((run + 127) & ~127) >> 7;
          nvalid[bs]  = run;
        }
      }
    }
    __syncthreads();

    const int j = j0 + (threadIdx.x >> 5);
    if (j >= s_pad32) return;                // never staged by maxsim
    const int l32 = threadIdx.x & 31;
    const int src_t = s_perm[threadIdx.x >> 5];
    const float* srcmat = side ? dn : dp;
    float4 v = make_float4(0.f, 0.f, 0.f, 0.f);
    if (src_t >= 0)
      v = ((const float4*)(srcmat + ((size_t)b * SDN + src_t) * HH))[l32];
    short4 o; o.x = f2bf(v.x); o.y = f2bf(v.y); o.z = f2bf(v.z); o.w = f2bf(v.w);
    *(short4*)&od[((size_t)bs * SDN + j) * HH + l32 * 4] = o;
  } else {
    if (blockIdx.x == D_BLOCKS && threadIdx.x == 0) *counter = 0;  // for maxsim ticket
    int i = (blockIdx.x - D_BLOCKS) * 256 + threadIdx.x;  // float4 index, exact
    float4 v = ((const float4*)q)[i];
    short4 o; o.x = f2bf(v.x); o.y = f2bf(v.y); o.z = f2bf(v.z); o.w = f2bf(v.w);
    *(short4*)&oq[i * 4] = o;
  }
}

// Persistent maxsim: grid 512 = (16 a-slices x 32 b-groups), 2 blocks/CU,
// double-buffered chunk pipeline crossing bs boundaries, one barrier/chunk.
//
// This round:
//  - staging trim: last chunk of each bs stages only ntt*32 rows
//    (its = ntt*2 loop iterations) -> no dead L2 reads past pad32.
//  - loss fused in via last-block ticket: scores stores -> __threadfence()
//    (L2 writeback, covers cross-XCD visibility) -> atomicAdd(counter);
//    block #511 acquire-fences and computes the loss with the EXACT
//    16-partial reduction tree of the old loss_kernel (bitwise identical).
//
// XCD swizzle: lid%8 picks the XCD; remap so each XCD owns 4 whole bgroups
// x 16 a-slices (4 MB d-working-set fits the per-XCD L2).
// Last-chunk t-tile trim: ceil((valid-128*tc)/32) tiles; skipped rows are
// zeros (or unstaged garbage never read) -> bit-exact.
// d_lds: 128x128 bf16 per buffer, 16B chunks XOR-swizzled (c^(r&15)):
// staging + ds_read_b128 conflict-free.
#define ITS_OF(bi_, tc_) \
  (((tc_) == nchv[bi_] - 1) ? (((nvv[bi_] - ((tc_) << 7) + 31) >> 5) << 1) : 8)

__global__ __launch_bounds__(256, 2)
void maxsim_kernel(const short* __restrict__ qb,
                   const short* __restrict__ dc,
                   const int* __restrict__ nchunks,
                   const int* __restrict__ nvalid,
                   float* __restrict__ scores,
                   int* __restrict__ counter,
                   float* __restrict__ out) {
  const int lid  = blockIdx.x + 16 * blockIdx.y;   // 0..511
  const int xcd  = lid & 7;
  const int slot = lid >> 3;                        // 0..63 within XCD
  const int aslc = slot & 15;
  const int bs0  = (xcd + 8 * (slot >> 4)) * 4;     // bgroup*4

  __shared__ __align__(16) short d_lds[2][128 * 128];  // 2 x 32 KB

  const int tid = threadIdx.x;
  const int ln  = tid & 63;
  const int w   = tid >> 6;
  const int l31 = ln & 31;
  const int kh  = ln >> 5;
  const int a   = aslc * 4 + w;  // this wave's query (owns all 64 s)

  int nchv[4], nvv[4];
  #pragma unroll
  for (int i = 0; i < 4; ++i) {
    nchv[i] = nchunks[bs0 + i];   // block-uniform
    nvv[i]  = nvalid[bs0 + i];
  }

  // ---- q as B-operand (persistent, from L2/LLC): n = half*32+l31, k = kc*16+kh*8 ----
  bf16x8 qfrag[2][8];
  #pragma unroll
  for (int half = 0; half < 2; ++half) {
    const short* qrow = qb + ((size_t)a * SQN + half * 32 + l31) * HH + kh * 8;
    #pragma unroll
    for (int kc = 0; kc < 8; ++kc)
      qfrag[half][kc] = *(const bf16x8*)(qrow + kc * 16);
  }

  float rmaxh[2] = {0.f, 0.f};   // masked-zero trick: true max >= 0

  int cur_its = ITS_OF(0, 0);

  // ---- stage chunk (bs0, 0) into buffer 0 (trimmed) ----
  {
    const short* dsrc = dc + (size_t)bs0 * SDN * HH;
    #pragma unroll
    for (int it = 0; it < 8; ++it) {
      if (it < cur_its) {
        int f = it * 256 + tid;
        int row = f >> 4;
        int c = (f & 15) ^ (row & 15);
        gl_lds16(&dsrc[row * HH + c * 8], &d_lds[0][(it * 256 + w * 64) * 8]);
      }
    }
  }
  __syncthreads();

  int bi = 0, tc = 0, buf = 0;
  for (;;) {
    // next flat chunk (possibly first chunk of next bs)
    int nbi = bi, ntc = tc + 1;
    if (ntc == nchv[bi]) { ntc = 0; nbi = bi + 1; }
    const bool hn = (nbi < 4);
    const int nxt_its = hn ? ITS_OF(nbi, ntc) : 0;

    // ---- issue prefetch BEFORE compute (drain lands after MFMA phase) ----
    if (hn) {
      const short* dsrc = dc + ((size_t)(bs0 + nbi) * SDN + ntc * 128) * HH;
      short* dst = &d_lds[buf ^ 1][0];
      #pragma unroll
      for (int it = 0; it < 8; ++it) {
        if (it < nxt_its) {
          int f = it * 256 + tid;
          int row = f >> 4;
          int c = (f & 15) ^ (row & 15);
          gl_lds16(&dsrc[row * HH + c * 8], &dst[(it * 256 + w * 64) * 8]);
        }
      }
    }

    // ---- compute: ntt t-tiles x 8 kc x 2 s-halves; C[m=t][n=s] ----
    const int ntt = cur_its >> 1;
    const short* bufp = &d_lds[buf][0];
    #pragma unroll
    for (int tt = 0; tt < 4; ++tt) {
      if (tt < ntt) {
        int trow = tt * 32 + l31;
        int tm = trow & 15;
        const short* bbase = &bufp[trow * HH];
        f32x16 acc0 = {0,0,0,0,0,0,0,0,0,0,0,0,0,0,0,0};
        f32x16 acc1 = {0,0,0,0,0,0,0,0,0,0,0,0,0,0,0,0};
        #pragma unroll
        for (int kc = 0; kc < 8; ++kc) {
          int c = (kc * 2 + kh) ^ tm;
          bf16x8 dfrag = *(const bf16x8*)&bbase[c * 8];  // A: m = t = trow
          acc0 = __builtin_amdgcn_mfma_f32_32x32x16_bf16(dfrag, qfrag[0][kc], acc0, 0, 0, 0);
          acc1 = __builtin_amdgcn_mfma_f32_32x32x16_bf16(dfrag, qfrag[1][kc], acc1, 0, 0, 0);
        }
        // C: col = l31 = s (within half), rows = 16 t's of this lane's kh group
        float m0 = acc0[0], m1 = acc1[0];
        #pragma unroll
        for (int r = 1; r < 16; ++r) {
          m0 = fmaxf(m0, acc0[r]);
          m1 = fmaxf(m1, acc1[r]);
        }
        rmaxh[0] = fmaxf(rmaxh[0], m0);
        rmaxh[1] = fmaxf(rmaxh[1], m1);
      }
    }

    // ---- finished bs(bi)? finalize: cross-kh max, then sum over s ----
    if (ntc == 0) {
      float v0 = fmaxf(rmaxh[0], __shfl_xor(rmaxh[0], 32));  // merge kh t-halves
      float v1 = fmaxf(rmaxh[1], __shfl_xor(rmaxh[1], 32));
      float s = v0 + v1;                 // s = l31 and s = 32+l31
      s += __shfl_xor(s, 1);  s += __shfl_xor(s, 2);  s += __shfl_xor(s, 4);
      s += __shfl_xor(s, 8);  s += __shfl_xor(s, 16);
      if (ln == 0) scores[(size_t)a * (2 * BB) + bs0 + bi] = s;
      rmaxh[0] = 0.f; rmaxh[1] = 0.f;
    }

    // barrier: all waves done reading buf before re-stage; drains prefetch
    __syncthreads();
    if (!hn) break;
    bi = nbi; tc = ntc; buf ^= 1; cur_its = nxt_its;
  }

  // ---- fused loss: last block to finish computes it ----
  __threadfence();                         // flush scores past this XCD's L2
  __shared__ int s_ticket;
  if (tid == 0) s_ticket = atomicAdd(counter, 1);
  __syncthreads();
  if (s_ticket != 511) return;
  __threadfence();                         // acquire side

  // Bitwise-identical replica of the old 16-wave loss reduction:
  // virtual part vp (0..15) = rows 4vp..4vp+3; wave w computes vp=4w..4w+3;
  // wave 0 then runs the exact 16-lane xor tree.
  __shared__ float part[16];
  #pragma unroll
  for (int q8 = 0; q8 < 4; ++q8) {
    int vp = w * 4 + q8;
    float acc = 0.f;
    #pragma unroll
    for (int i = 0; i < 4; ++i) {
      int r = vp * 4 + i;
      float v0 = __hip_atomic_load(&scores[r * 128 + ln],
                                   __ATOMIC_RELAXED, __HIP_MEMORY_SCOPE_AGENT);
      float v1 = __hip_atomic_load(&scores[r * 128 + 64 + ln],
                                   __ATOMIC_RELAXED, __HIP_MEMORY_SCOPE_AGENT);
      float mx = fmaxf(v0, v1);
      #pragma unroll
      for (int off = 32; off >= 1; off >>= 1) mx = fmaxf(mx, __shfl_xor(mx, off));
      float e = __expf(v0 - mx) + __expf(v1 - mx);
      #pragma unroll
      for (int off = 32; off >= 1; off >>= 1) e += __shfl_xor(e, off);
      float lse = mx + __logf(e);
      float diag = __shfl(v0, r);   // r < 64, diagonal lives in v0 at lane r
      acc += lse - diag;
    }
    if (ln == 0) part[vp] = acc;
  }
  __syncthreads();
  if (w == 0) {
    float v = (ln < 16) ? part[ln] : 0.f;
    #pragma unroll
    for (int off = 8; off >= 1; off >>= 1) v += __shfl_xor(v, off);
    if (ln == 0) out[0] = v * (1.0f / 64.0f);
  }
}

extern "C" void kernel_launch(void* const* d_in, const int* in_sizes, int n_in,
                              void* d_out, int out_size, void* d_ws, size_t ws_size,
                              hipStream_t stream) {
  const float* q        = (const float*)d_in[0];
  const float* d_pos    = (const float*)d_in[1];
  const float* d_neg    = (const float*)d_in[2];
  const int*   mask_pos = (const int*)d_in[3];
  const int*   mask_neg = (const int*)d_in[4];

  // ws layout: q_bf 1 MB | d_c 16 MB | nchunks | nvalid | scores | counter
  short* q_bf = (short*)d_ws;                                  // 524288 shorts
  short* d_c  = q_bf + (size_t)BB * SQN * HH;                  // 8388608 shorts
  int*   nchunks = (int*)(d_c + (size_t)2 * BB * SDN * HH);    // 128 ints
  int*   nvalid  = nchunks + 128;                              // 128 ints
  float* scores  = (float*)(nvalid + 128);                     // 8192 floats
  int*   counter = (int*)(scores + 64 * 128);                  // 1 int

  const int D_BLOCKS = (2 * BB * SDN) / 8;          // 8192
  const int Q_BLOCKS = (BB * SQN * HH / 4) / 256;   // 512
  convert_all<<<D_BLOCKS + Q_BLOCKS, 256, 0, stream>>>(
      q, d_pos, d_neg, mask_pos, mask_neg, q_bf, d_c, nchunks, nvalid, counter);

  dim3 grid(16 /*a-slices*/, 32 /*b-groups*/);
  maxsim_kernel<<<grid, 256, 0, stream>>>(q_bf, d_c, nchunks, nvalid, scores,
                                          counter, (float*)d_out);
}

// Round 3
// 125.927 us; speedup vs baseline: 1.2348x; 1.2348x over previous
//
#include <hip/hip_runtime.h>
#include <hip/hip_bf16.h>
#include <math.h>
#include <stdint.h>

// Problem: B=64, SQ=64, SD=512, H=128
#define BB 64
#define SQN 64
#define SDN 512
#define HH 128

typedef __attribute__((ext_vector_type(8))) short bf16x8;     // 8 bf16 = 4 VGPRs
typedef __attribute__((ext_vector_type(16))) float f32x16;    // 16 acc regs

__device__ __forceinline__ short f2bf(float f) {
  union { float f; unsigned u; } x; x.f = f;
  unsigned r = x.u + 0x7fffu + ((x.u >> 16) & 1u);   // RNE
  return (short)(r >> 16);
}

__device__ __forceinline__ void gl_lds16(const short* g, short* l) {
  __builtin_amdgcn_global_load_lds(
      (const __attribute__((address_space(1))) unsigned int*)g,
      (__attribute__((address_space(3))) unsigned int*)l, 16, 0, 0);
}

// ---- fused compact + fp32->bf16 convert ------------------------------------
// d-blocks (8 rows each) recompute their own perm slice with an in-wave
// ballot/popcount scan of the 512-entry mask row (L2-hot, hidden under the
// block's gather latency). One block per bs (j0==0) publishes nchunks/nvalid.
// Rows are written only up to pad32 = (valid+31)&~31: maxsim's trimmed
// staging never touches [pad32, pad128).
__global__ __launch_bounds__(256)
void convert_all(const float* __restrict__ q, const float* __restrict__ dp,
                 const float* __restrict__ dn,
                 const int* __restrict__ mp, const int* __restrict__ mn,
                 short* __restrict__ oq, short* __restrict__ od,
                 int* __restrict__ nchunks, int* __restrict__ nvalid,
                 int* __restrict__ counter) {
  const int D_BLOCKS = (2 * BB * SDN) / 8;   // 8192 (8 rows/block, 32 thr/row)
  if (blockIdx.x < D_BLOCKS) {
    const int bs = blockIdx.x >> 6;          // 64 blocks per (side*64+b)
    const int j0 = (blockIdx.x & 63) * 8;    // first compacted row of block
    const int side = bs >> 6, b = bs & 63;
    const int* mask = (side ? mn : mp) + b * SDN;

    __shared__ int s_perm[8];
    __shared__ int s_pad32;

    if (threadIdx.x < 64) {                  // wave 0: exclusive scan of mask
      const int ln = threadIdx.x;
      int mreg[8];
      #pragma unroll
      for (int it = 0; it < 8; ++it) mreg[it] = mask[it * 64 + ln];
      int run = 0;
      #pragma unroll
      for (int it = 0; it < 8; ++it) {
        unsigned long long bal = __ballot(mreg[it] != 0);
        int pos = run + __popcll(bal & ((1ull << ln) - 1ull));
        if (mreg[it]) {
          unsigned rel = (unsigned)(pos - j0);
          if (rel < 8u) s_perm[rel] = it * 64 + ln;
        }
        run += (int)__popcll(bal);
      }
      if (ln < 8 && j0 + ln >= run) s_perm[ln] = -1;   // zero-fill slots
      if (ln == 0) {
        s_pad32 = (run + 31) & ~31;
        if (j0 == 0) {                       // one writer per bs
          nchunks[bs] = ((run + 127) & ~127) >> 7;
          nvalid[bs]  = run;
        }
      }
    }
    __syncthreads();

    const int j = j0 + (threadIdx.x >> 5);
    if (j >= s_pad32) return;                // never staged by maxsim
    const int l32 = threadIdx.x & 31;
    const int src_t = s_perm[threadIdx.x >> 5];
    const float* srcmat = side ? dn : dp;
    float4 v = make_float4(0.f, 0.f, 0.f, 0.f);
    if (src_t >= 0)
      v = ((const float4*)(srcmat + ((size_t)b * SDN + src_t) * HH))[l32];
    short4 o; o.x = f2bf(v.x); o.y = f2bf(v.y); o.z = f2bf(v.z); o.w = f2bf(v.w);
    *(short4*)&od[((size_t)bs * SDN + j) * HH + l32 * 4] = o;
  } else {
    if (blockIdx.x == D_BLOCKS && threadIdx.x == 0) *counter = 0;  // for maxsim ticket
    int i = (blockIdx.x - D_BLOCKS) * 256 + threadIdx.x;  // float4 index, exact
    float4 v = ((const float4*)q)[i];
    short4 o; o.x = f2bf(v.x); o.y = f2bf(v.y); o.z = f2bf(v.z); o.w = f2bf(v.w);
    *(short4*)&oq[i * 4] = o;
  }
}

// Persistent maxsim: grid 512 = (16 a-slices x 32 b-groups), 2 blocks/CU,
// double-buffered chunk pipeline crossing bs boundaries, one barrier/chunk.
//
// ROUND-2 POST-MORTEM / THIS ROUND'S FIX: round 2 fused the loss via
// per-block __threadfence(), which on multi-XCD gfx950 emits buffer_wbl2 +
// buffer_inv (full L2 writeback + invalidate). 512 staggered finishing
// blocks each nuked their XCD's L2 copy of d_c for still-running siblings
// -> maxsim 40->88us, MfmaUtil 16%, all pipes idle. Fix: cache-op-FREE
// handoff. scores are written with agent-scope RELAXED atomic stores
// (global_store sc1: write-through to the coherent LLC, no L2 writeback),
// ordered before the ticket by a plain s_waitcnt vmcnt(0); the ticket is a
// RELAXED agent fetch_add (LLC atomic); the reader uses sc1 relaxed atomic
// loads (read LLC directly, no buffer_inv). No full-cache ops anywhere.
//
// XCD swizzle: lid%8 picks the XCD; remap so each XCD owns 4 whole bgroups
// x 16 a-slices (4 MB d-working-set fits the per-XCD L2).
// Last-chunk trim: stage + compute only ceil((valid-128*tc)/32) 32-row
// t-tiles; skipped rows are zeros or never read -> bit-exact.
// d_lds: 128x128 bf16 per buffer, 16B chunks XOR-swizzled (c^(r&15)):
// staging + ds_read_b128 conflict-free.
#define ITS_OF(bi_, tc_) \
  (((tc_) == nchv[bi_] - 1) ? (((nvv[bi_] - ((tc_) << 7) + 31) >> 5) << 1) : 8)

__global__ __launch_bounds__(256, 2)
void maxsim_kernel(const short* __restrict__ qb,
                   const short* __restrict__ dc,
                   const int* __restrict__ nchunks,
                   const int* __restrict__ nvalid,
                   float* __restrict__ scores,
                   int* __restrict__ counter,
                   float* __restrict__ out) {
  const int lid  = blockIdx.x + 16 * blockIdx.y;   // 0..511
  const int xcd  = lid & 7;
  const int slot = lid >> 3;                        // 0..63 within XCD
  const int aslc = slot & 15;
  const int bs0  = (xcd + 8 * (slot >> 4)) * 4;     // bgroup*4

  __shared__ __align__(16) short d_lds[2][128 * 128];  // 2 x 32 KB

  const int tid = threadIdx.x;
  const int ln  = tid & 63;
  const int w   = tid >> 6;
  const int l31 = ln & 31;
  const int kh  = ln >> 5;
  const int a   = aslc * 4 + w;  // this wave's query (owns all 64 s)

  int nchv[4], nvv[4];
  #pragma unroll
  for (int i = 0; i < 4; ++i) {
    nchv[i] = nchunks[bs0 + i];   // block-uniform
    nvv[i]  = nvalid[bs0 + i];
  }

  // ---- q as B-operand (persistent, from L2/LLC): n = half*32+l31, k = kc*16+kh*8 ----
  bf16x8 qfrag[2][8];
  #pragma unroll
  for (int half = 0; half < 2; ++half) {
    const short* qrow = qb + ((size_t)a * SQN + half * 32 + l31) * HH + kh * 8;
    #pragma unroll
    for (int kc = 0; kc < 8; ++kc)
      qfrag[half][kc] = *(const bf16x8*)(qrow + kc * 16);
  }

  float rmaxh[2] = {0.f, 0.f};   // masked-zero trick: true max >= 0

  int cur_its = ITS_OF(0, 0);

  // ---- stage chunk (bs0, 0) into buffer 0 (trimmed) ----
  {
    const short* dsrc = dc + (size_t)bs0 * SDN * HH;
    #pragma unroll
    for (int it = 0; it < 8; ++it) {
      if (it < cur_its) {
        int f = it * 256 + tid;
        int row = f >> 4;
        int c = (f & 15) ^ (row & 15);
        gl_lds16(&dsrc[row * HH + c * 8], &d_lds[0][(it * 256 + w * 64) * 8]);
      }
    }
  }
  __syncthreads();

  int bi = 0, tc = 0, buf = 0;
  for (;;) {
    // next flat chunk (possibly first chunk of next bs)
    int nbi = bi, ntc = tc + 1;
    if (ntc == nchv[bi]) { ntc = 0; nbi = bi + 1; }
    const bool hn = (nbi < 4);
    const int nxt_its = hn ? ITS_OF(nbi, ntc) : 0;

    // ---- issue prefetch BEFORE compute (drain lands after MFMA phase) ----
    if (hn) {
      const short* dsrc = dc + ((size_t)(bs0 + nbi) * SDN + ntc * 128) * HH;
      short* dst = &d_lds[buf ^ 1][0];
      #pragma unroll
      for (int it = 0; it < 8; ++it) {
        if (it < nxt_its) {
          int f = it * 256 + tid;
          int row = f >> 4;
          int c = (f & 15) ^ (row & 15);
          gl_lds16(&dsrc[row * HH + c * 8], &dst[(it * 256 + w * 64) * 8]);
        }
      }
    }

    // ---- compute: ntt t-tiles x 8 kc x 2 s-halves; C[m=t][n=s] ----
    const int ntt = cur_its >> 1;
    const short* bufp = &d_lds[buf][0];
    #pragma unroll
    for (int tt = 0; tt < 4; ++tt) {
      if (tt < ntt) {
        int trow = tt * 32 + l31;
        int tm = trow & 15;
        const short* bbase = &bufp[trow * HH];
        f32x16 acc0 = {0,0,0,0,0,0,0,0,0,0,0,0,0,0,0,0};
        f32x16 acc1 = {0,0,0,0,0,0,0,0,0,0,0,0,0,0,0,0};
        #pragma unroll
        for (int kc = 0; kc < 8; ++kc) {
          int c = (kc * 2 + kh) ^ tm;
          bf16x8 dfrag = *(const bf16x8*)&bbase[c * 8];  // A: m = t = trow
          acc0 = __builtin_amdgcn_mfma_f32_32x32x16_bf16(dfrag, qfrag[0][kc], acc0, 0, 0, 0);
          acc1 = __builtin_amdgcn_mfma_f32_32x32x16_bf16(dfrag, qfrag[1][kc], acc1, 0, 0, 0);
        }
        // C: col = l31 = s (within half), rows = 16 t's of this lane's kh group
        float m0 = acc0[0], m1 = acc1[0];
        #pragma unroll
        for (int r = 1; r < 16; ++r) {
          m0 = fmaxf(m0, acc0[r]);
          m1 = fmaxf(m1, acc1[r]);
        }
        rmaxh[0] = fmaxf(rmaxh[0], m0);
        rmaxh[1] = fmaxf(rmaxh[1], m1);
      }
    }

    // ---- finished bs(bi)? finalize: cross-kh max, then sum over s ----
    if (ntc == 0) {
      float v0 = fmaxf(rmaxh[0], __shfl_xor(rmaxh[0], 32));  // merge kh t-halves
      float v1 = fmaxf(rmaxh[1], __shfl_xor(rmaxh[1], 32));
      float s = v0 + v1;                 // s = l31 and s = 32+l31
      s += __shfl_xor(s, 1);  s += __shfl_xor(s, 2);  s += __shfl_xor(s, 4);
      s += __shfl_xor(s, 8);  s += __shfl_xor(s, 16);
      if (ln == 0)
        __hip_atomic_store(&scores[(size_t)a * (2 * BB) + bs0 + bi], s,
                           __ATOMIC_RELAXED, __HIP_MEMORY_SCOPE_AGENT);
      rmaxh[0] = 0.f; rmaxh[1] = 0.f;
    }

    // barrier: all waves done reading buf before re-stage; drains prefetch
    __syncthreads();
    if (!hn) break;
    bi = nbi; tc = ntc; buf ^= 1; cur_its = nxt_its;
  }

  // ---- fused loss: last block to finish computes it (cache-op-free) ----
  // sc1 scores stores above write through to the LLC (coherence point);
  // vmcnt(0) guarantees they've arrived before the ticket increments.
  asm volatile("s_waitcnt vmcnt(0)" ::: "memory");
  __shared__ int s_ticket;
  if (tid == 0)
    s_ticket = __hip_atomic_fetch_add(counter, 1,
                                      __ATOMIC_RELAXED, __HIP_MEMORY_SCOPE_AGENT);
  __syncthreads();
  if (s_ticket != 511) return;

  // Bitwise-identical replica of the old 16-wave loss reduction:
  // part[vp] (vp=0..15) covers rows 4vp..4vp+3; wave w computes vp=4w..4w+3;
  // wave 0 then runs the exact 16-lane xor tree. sc1 loads read the LLC.
  __shared__ float part[16];
  #pragma unroll
  for (int q8 = 0; q8 < 4; ++q8) {
    int vp = w * 4 + q8;
    float acc = 0.f;
    #pragma unroll
    for (int i = 0; i < 4; ++i) {
      int r = vp * 4 + i;
      float v0 = __hip_atomic_load(&scores[r * 128 + ln],
                                   __ATOMIC_RELAXED, __HIP_MEMORY_SCOPE_AGENT);
      float v1 = __hip_atomic_load(&scores[r * 128 + 64 + ln],
                                   __ATOMIC_RELAXED, __HIP_MEMORY_SCOPE_AGENT);
      float mx = fmaxf(v0, v1);
      #pragma unroll
      for (int off = 32; off >= 1; off >>= 1) mx = fmaxf(mx, __shfl_xor(mx, off));
      float e = __expf(v0 - mx) + __expf(v1 - mx);
      #pragma unroll
      for (int off = 32; off >= 1; off >>= 1) e += __shfl_xor(e, off);
      float lse = mx + __logf(e);
      float diag = __shfl(v0, r);   // r < 64, diagonal lives in v0 at lane r
      acc += lse - diag;
    }
    if (ln == 0) part[vp] = acc;
  }
  __syncthreads();
  if (w == 0) {
    float v = (ln < 16) ? part[ln] : 0.f;
    #pragma unroll
    for (int off = 8; off >= 1; off >>= 1) v += __shfl_xor(v, off);
    if (ln == 0) out[0] = v * (1.0f / 64.0f);
  }
}

extern "C" void kernel_launch(void* const* d_in, const int* in_sizes, int n_in,
                              void* d_out, int out_size, void* d_ws, size_t ws_size,
                              hipStream_t stream) {
  const float* q        = (const float*)d_in[0];
  const float* d_pos    = (const float*)d_in[1];
  const float* d_neg    = (const float*)d_in[2];
  const int*   mask_pos = (const int*)d_in[3];
  const int*   mask_neg = (const int*)d_in[4];

  // ws layout: q_bf 1 MB | d_c 16 MB | nchunks | nvalid | scores | counter
  short* q_bf = (short*)d_ws;                                  // 524288 shorts
  short* d_c  = q_bf + (size_t)BB * SQN * HH;                  // 8388608 shorts
  int*   nchunks = (int*)(d_c + (size_t)2 * BB * SDN * HH);    // 128 ints
  int*   nvalid  = nchunks + 128;                              // 128 ints
  float* scores  = (float*)(nvalid + 128);                     // 8192 floats
  int*   counter = (int*)(scores + 64 * 128);                  // 1 int

  const int D_BLOCKS = (2 * BB * SDN) / 8;          // 8192
  const int Q_BLOCKS = (BB * SQN * HH / 4) / 256;   // 512
  convert_all<<<D_BLOCKS + Q_BLOCKS, 256, 0, stream>>>(
      q, d_pos, d_neg, mask_pos, mask_neg, q_bf, d_c, nchunks, nvalid, counter);

  dim3 grid(16 /*a-slices*/, 32 /*b-groups*/);
  maxsim_kernel<<<grid, 256, 0, stream>>>(q_bf, d_c, nchunks, nvalid, scores,
                                          counter, (float*)d_out);
}